// Round 1
// baseline (266.148 us; speedup 1.0000x reference)
//
#include <hip/hip_runtime.h>
#include <stdint.h>

typedef __attribute__((ext_vector_type(8))) short short8v;
typedef __attribute__((ext_vector_type(4))) float float4v;
typedef __attribute__((ext_vector_type(4))) unsigned short ushort4v;

#define B_SZ 2
#define T_SEQ 2048
#define C_EMB 1024
#define NH 16
#define DH 64
#define M_ROWS (B_SZ * T_SEQ)

__device__ __forceinline__ unsigned short f2bf(float f) {
    unsigned int u = __float_as_uint(f);
    u += 0x7FFFu + ((u >> 16) & 1u);   // RTNE
    return (unsigned short)(u >> 16);
}

__device__ __forceinline__ void gload_lds16(const void* g, void* s) {
    __builtin_amdgcn_global_load_lds(
        (const __attribute__((address_space(1))) void*)g,
        (__attribute__((address_space(3))) void*)s, 16, 0, 0);
}

// ---------------- x f32 -> bf16 ----------------
__global__ __launch_bounds__(256) void k_cvt_x(const float* __restrict__ in,
                                               unsigned short* __restrict__ out, int n4) {
    int i = blockIdx.x * 256 + threadIdx.x;
    if (i >= n4) return;
    float4v v = ((const float4v*)in)[i];
    ushort4v o;
    o.x = f2bf(v.x); o.y = f2bf(v.y); o.z = f2bf(v.z); o.w = f2bf(v.w);
    ((ushort4v*)out)[i] = o;
}

// ------------- W f32 [R][C] -> bf16 [C][R] -------------
__global__ __launch_bounds__(256) void k_transpose_cvt(const float* __restrict__ in,
                                                       unsigned short* __restrict__ out,
                                                       int R, int C) {
    __shared__ float tile[64][65];
    int c0 = blockIdx.x * 64;
    int r0 = blockIdx.y * 64;
#pragma unroll
    for (int i = 0; i < 16; ++i) {
        int e = i * 256 + threadIdx.x;
        int r = e >> 6, c = e & 63;
        tile[r][c] = in[(size_t)(r0 + r) * C + c0 + c];
    }
    __syncthreads();
#pragma unroll
    for (int i = 0; i < 16; ++i) {
        int e = i * 256 + threadIdx.x;
        int r = e >> 6, c = e & 63;
        out[(size_t)(c0 + r) * R + r0 + c] = f2bf(tile[c][r]);
    }
}

// ------------- GEMM: C[M][N] = A[M][K] * Bt[N][K]^T (bf16 in, bf16/f32 out) -------------
__global__ __launch_bounds__(256) void k_gemm_bt(const unsigned short* __restrict__ A,
                                                 const unsigned short* __restrict__ Bt,
                                                 void* __restrict__ Cout,
                                                 int M, int N, int K, int out_f32) {
    __shared__ __align__(16) unsigned short As[128 * 32];
    __shared__ __align__(16) unsigned short Bs[128 * 32];

    const int tid = threadIdx.x;
    const int lane = tid & 63;
    const int w = tid >> 6;
    const int lr = lane & 15;
    const int lg = lane >> 4;
    const int wr = (w >> 1) * 64;
    const int wc = (w & 1) * 64;

    const int m0 = blockIdx.y * 128;
    const int n0 = blockIdx.x * 128;

    const unsigned short* aptr = A + (size_t)(m0 + (tid >> 2)) * K + (tid & 3) * 8;
    const unsigned short* bptr = Bt + (size_t)(n0 + (tid >> 2)) * K + (tid & 3) * 8;

    float4v acc[4][4];
#pragma unroll
    for (int i = 0; i < 4; ++i)
#pragma unroll
        for (int j = 0; j < 4; ++j) acc[i][j] = (float4v){0.f, 0.f, 0.f, 0.f};

    for (int k0 = 0; k0 < K; k0 += 32) {
        gload_lds16(aptr + k0, &As[tid * 8]);
        gload_lds16(aptr + (size_t)64 * K + k0, &As[2048 + tid * 8]);
        gload_lds16(bptr + k0, &Bs[tid * 8]);
        gload_lds16(bptr + (size_t)64 * K + k0, &Bs[2048 + tid * 8]);
        __syncthreads();

        short8v af[4], bf[4];
#pragma unroll
        for (int i = 0; i < 4; ++i)
            af[i] = *(const short8v*)&As[(wr + i * 16 + lr) * 32 + lg * 8];
#pragma unroll
        for (int i = 0; i < 4; ++i)
            bf[i] = *(const short8v*)&Bs[(wc + i * 16 + lr) * 32 + lg * 8];
#pragma unroll
        for (int mi = 0; mi < 4; ++mi)
#pragma unroll
            for (int ni = 0; ni < 4; ++ni)
                acc[mi][ni] = __builtin_amdgcn_mfma_f32_16x16x32_bf16(af[mi], bf[ni],
                                                                      acc[mi][ni], 0, 0, 0);
        __syncthreads();
    }

#pragma unroll
    for (int mi = 0; mi < 4; ++mi) {
#pragma unroll
        for (int ni = 0; ni < 4; ++ni) {
            int row = m0 + wr + mi * 16 + lg * 4;
            int col = n0 + wc + ni * 16 + lr;
            if (out_f32) {
                float* Cf = (float*)Cout;
#pragma unroll
                for (int r = 0; r < 4; ++r) Cf[(size_t)(row + r) * N + col] = acc[mi][ni][r];
            } else {
                unsigned short* Cb = (unsigned short*)Cout;
#pragma unroll
                for (int r = 0; r < 4; ++r) Cb[(size_t)(row + r) * N + col] = f2bf(acc[mi][ni][r]);
            }
        }
    }
}

// ------------- V-part of qkv -> v_t[b,h,d,t] (bf16) -------------
__global__ __launch_bounds__(256) void k_transpose_v(const unsigned short* __restrict__ qkv,
                                                     unsigned short* __restrict__ vt) {
    __shared__ unsigned short tile[64][72];
    int t0 = blockIdx.x * 64;
    int bh = blockIdx.y;
    int b = bh >> 4, h = bh & 15;
#pragma unroll
    for (int i = 0; i < 2; ++i) {
        int e = i * 256 + threadIdx.x;
        int tt = e >> 3, db = (e & 7) * 8;
        short8v v = *(const short8v*)&qkv[(size_t)(b * T_SEQ + t0 + tt) * (3 * C_EMB)
                                          + 2 * C_EMB + h * DH + db];
#pragma unroll
        for (int j = 0; j < 8; ++j) tile[tt][db + j] = (unsigned short)v[j];
    }
    __syncthreads();
#pragma unroll
    for (int i = 0; i < 2; ++i) {
        int e = i * 256 + threadIdx.x;
        int d = e >> 3, tb = (e & 7) * 8;
        short8v ov;
#pragma unroll
        for (int j = 0; j < 8; ++j) ov[j] = (short)tile[tb + j][d];
        *(short8v*)&vt[(size_t)(bh * DH + d) * T_SEQ + t0 + tb] = ov;
    }
}

// ------------- flash attention -------------
__global__ __launch_bounds__(256) void k_attn(const unsigned short* __restrict__ qkv,
                                              const unsigned short* __restrict__ vt,
                                              unsigned short* __restrict__ aout) {
    __shared__ __align__(16) unsigned short Ks[32 * 64];   // [key][dim]
    __shared__ __align__(16) unsigned short Vs[64 * 32];   // [dim][key]
    __shared__ __align__(16) unsigned short Ps[4][16 * 32];

    const int tid = threadIdx.x;
    const int lane = tid & 63;
    const int w = tid >> 6;
    const int lr = lane & 15;
    const int lg = lane >> 4;

    const int q0 = ((int)gridDim.x - 1 - (int)blockIdx.x) * 64;  // heavy blocks first
    const int bh = blockIdx.y;
    const int b = bh >> 4, h = bh & 15;

    const unsigned short* qrowp =
        qkv + (size_t)(b * T_SEQ + q0 + w * 16 + lr) * (3 * C_EMB) + h * DH + lg * 8;
    short8v qa0 = *(const short8v*)qrowp;
    short8v qa1 = *(const short8v*)(qrowp + 32);

    float4v o[4];
    float m_run[4], l_run[4];
#pragma unroll
    for (int n = 0; n < 4; ++n) o[n] = (float4v){0.f, 0.f, 0.f, 0.f};
#pragma unroll
    for (int r = 0; r < 4; ++r) { m_run[r] = -1e30f; l_run[r] = 0.f; }

    const unsigned short* kbase =
        qkv + (size_t)(b * T_SEQ + (tid >> 3)) * (3 * C_EMB) + C_EMB + h * DH + (tid & 7) * 8;
    const unsigned short* vbase =
        vt + (size_t)(bh * DH + (tid >> 2)) * T_SEQ + (tid & 3) * 8;

    const int kv_end = q0 + 64;
    for (int kv0 = 0; kv0 < kv_end; kv0 += 32) {
        gload_lds16(kbase + (size_t)kv0 * (3 * C_EMB), &Ks[tid * 8]);
        gload_lds16(vbase + kv0, &Vs[tid * 8]);
        __syncthreads();

        float4v s0 = (float4v){0.f, 0.f, 0.f, 0.f}, s1 = s0;
        {
            short8v kb;
            kb = *(const short8v*)&Ks[(0 * 16 + lr) * 64 + lg * 8];
            s0 = __builtin_amdgcn_mfma_f32_16x16x32_bf16(qa0, kb, s0, 0, 0, 0);
            kb = *(const short8v*)&Ks[(0 * 16 + lr) * 64 + 32 + lg * 8];
            s0 = __builtin_amdgcn_mfma_f32_16x16x32_bf16(qa1, kb, s0, 0, 0, 0);
            kb = *(const short8v*)&Ks[(1 * 16 + lr) * 64 + lg * 8];
            s1 = __builtin_amdgcn_mfma_f32_16x16x32_bf16(qa0, kb, s1, 0, 0, 0);
            kb = *(const short8v*)&Ks[(1 * 16 + lr) * 64 + 32 + lg * 8];
            s1 = __builtin_amdgcn_mfma_f32_16x16x32_bf16(qa1, kb, s1, 0, 0, 0);
        }

        const int qr = q0 + w * 16 + lg * 4;
        float alpha[4], rowsum[4], rmax[4];
#pragma unroll
        for (int r = 0; r < 4; ++r) {
            int kc = kv0 + lr;
            float v0 = s0[r] * 0.125f;
            float v1 = s1[r] * 0.125f;
            s0[r] = (kc <= qr + r) ? v0 : -1e30f;
            s1[r] = (kc + 16 <= qr + r) ? v1 : -1e30f;
            rmax[r] = fmaxf(s0[r], s1[r]);
        }
#pragma unroll
        for (int st = 1; st < 16; st <<= 1) {
#pragma unroll
            for (int r = 0; r < 4; ++r)
                rmax[r] = fmaxf(rmax[r], __shfl_xor(rmax[r], st));
        }
#pragma unroll
        for (int r = 0; r < 4; ++r) {
            float mn = fmaxf(m_run[r], rmax[r]);
            alpha[r] = __expf(m_run[r] - mn);
            m_run[r] = mn;
            float p0 = __expf(s0[r] - mn);
            float p1 = __expf(s1[r] - mn);
            s0[r] = p0; s1[r] = p1;
            rowsum[r] = p0 + p1;
        }
#pragma unroll
        for (int st = 1; st < 16; st <<= 1) {
#pragma unroll
            for (int r = 0; r < 4; ++r)
                rowsum[r] += __shfl_xor(rowsum[r], st);
        }
#pragma unroll
        for (int r = 0; r < 4; ++r) l_run[r] = l_run[r] * alpha[r] + rowsum[r];
#pragma unroll
        for (int n = 0; n < 4; ++n)
#pragma unroll
            for (int r = 0; r < 4; ++r) o[n][r] *= alpha[r];

#pragma unroll
        for (int r = 0; r < 4; ++r) {
            Ps[w][(lg * 4 + r) * 32 + lr] = f2bf(s0[r]);
            Ps[w][(lg * 4 + r) * 32 + 16 + lr] = f2bf(s1[r]);
        }
        __syncthreads();

        short8v pa = *(const short8v*)&Ps[w][lr * 32 + lg * 8];
#pragma unroll
        for (int n = 0; n < 4; ++n) {
            short8v vb = *(const short8v*)&Vs[(n * 16 + lr) * 32 + lg * 8];
            o[n] = __builtin_amdgcn_mfma_f32_16x16x32_bf16(pa, vb, o[n], 0, 0, 0);
        }
        __syncthreads();
    }

    const int trow = b * T_SEQ + q0 + w * 16 + lg * 4;
#pragma unroll
    for (int n = 0; n < 4; ++n) {
#pragma unroll
        for (int r = 0; r < 4; ++r) {
            float val = o[n][r] / l_run[r];
            aout[(size_t)(trow + r) * C_EMB + h * DH + n * 16 + lr] = f2bf(val);
        }
    }
}

extern "C" void kernel_launch(void* const* d_in, const int* in_sizes, int n_in,
                              void* d_out, int out_size, void* d_ws, size_t ws_size,
                              hipStream_t stream) {
    const float* x = (const float*)d_in[0];
    const float* Wqkv = (const float*)d_in[1];
    const float* Wproj = (const float*)d_in[2];
    float* out = (float*)d_out;

    unsigned short* xb     = (unsigned short*)d_ws;
    unsigned short* wqkvT  = xb + (size_t)M_ROWS * C_EMB;
    unsigned short* wprojT = wqkvT + (size_t)3 * C_EMB * C_EMB;
    unsigned short* qkvb   = wprojT + (size_t)C_EMB * C_EMB;
    unsigned short* vtb    = qkvb + (size_t)M_ROWS * 3 * C_EMB;
    unsigned short* attb   = vtb + (size_t)M_ROWS * C_EMB;

    k_cvt_x<<<(M_ROWS * C_EMB / 4 + 255) / 256, 256, 0, stream>>>(x, xb, M_ROWS * C_EMB / 4);
    k_transpose_cvt<<<dim3(3 * C_EMB / 64, C_EMB / 64), 256, 0, stream>>>(Wqkv, wqkvT, C_EMB, 3 * C_EMB);
    k_transpose_cvt<<<dim3(C_EMB / 64, C_EMB / 64), 256, 0, stream>>>(Wproj, wprojT, C_EMB, C_EMB);
    k_gemm_bt<<<dim3(3 * C_EMB / 128, M_ROWS / 128), 256, 0, stream>>>(xb, wqkvT, (void*)qkvb,
                                                                       M_ROWS, 3 * C_EMB, C_EMB, 0);
    k_transpose_v<<<dim3(T_SEQ / 64, B_SZ * NH), 256, 0, stream>>>(qkvb, vtb);
    k_attn<<<dim3(T_SEQ / 64, B_SZ * NH), 256, 0, stream>>>(qkvb, vtb, attb);
    k_gemm_bt<<<dim3(C_EMB / 128, M_ROWS / 128), 256, 0, stream>>>(attb, wprojT, (void*)out,
                                                                   M_ROWS, C_EMB, C_EMB, 1);
}

// Round 3
// 142.899 us; speedup vs baseline: 1.8625x; 1.8625x over previous
//
#include <hip/hip_runtime.h>
#include <stdint.h>

typedef __attribute__((ext_vector_type(8))) short short8v;
typedef __attribute__((ext_vector_type(4))) float float4v;
typedef __attribute__((ext_vector_type(4))) unsigned short ushort4v;

#define B_SZ 2
#define T_SEQ 2048
#define C_EMB 1024
#define NH 16
#define DH 64
#define M_ROWS (B_SZ * T_SEQ)
#define CEXP 0.18033688f        /* (1/sqrt(64)) * log2(e) */
#define DEFER_THR 44.3614f      /* 8 / CEXP */

__device__ __forceinline__ unsigned short f2bf(float f) {
    unsigned int u = __float_as_uint(f);
    u += 0x7FFFu + ((u >> 16) & 1u);   // RTNE
    return (unsigned short)(u >> 16);
}

__device__ __forceinline__ unsigned int cvtpk_bf16(float lo, float hi) {
    unsigned int r;
    asm("v_cvt_pk_bf16_f32 %0, %1, %2" : "=v"(r) : "v"(lo), "v"(hi));
    return r;
}

__device__ __forceinline__ void gload_lds16(const void* g, void* s) {
    __builtin_amdgcn_global_load_lds(
        (const __attribute__((address_space(1))) void*)g,
        (__attribute__((address_space(3))) void*)s, 16, 0, 0);
}

__device__ __forceinline__ void memfence_sched() { asm volatile("" ::: "memory"); }

__device__ __forceinline__ void block_barrier() {
    memfence_sched();
    __builtin_amdgcn_s_barrier();
    memfence_sched();
}

// ---------------- x f32 -> bf16 ----------------
__global__ __launch_bounds__(256) void k_cvt_x(const float* __restrict__ in,
                                               unsigned short* __restrict__ out, int n4) {
    int i = blockIdx.x * 256 + threadIdx.x;
    if (i >= n4) return;
    float4v v = ((const float4v*)in)[i];
    ushort4v o;
    o.x = f2bf(v.x); o.y = f2bf(v.y); o.z = f2bf(v.z); o.w = f2bf(v.w);
    ((ushort4v*)out)[i] = o;
}

// ------------- W f32 [R][C] -> bf16 [C][R] -------------
__global__ __launch_bounds__(256) void k_transpose_cvt(const float* __restrict__ in,
                                                       unsigned short* __restrict__ out,
                                                       int R, int C) {
    __shared__ float tile[64][65];
    int c0 = blockIdx.x * 64;
    int r0 = blockIdx.y * 64;
#pragma unroll
    for (int i = 0; i < 16; ++i) {
        int e = i * 256 + threadIdx.x;
        int r = e >> 6, c = e & 63;
        tile[r][c] = in[(size_t)(r0 + r) * C + c0 + c];
    }
    __syncthreads();
#pragma unroll
    for (int i = 0; i < 16; ++i) {
        int e = i * 256 + threadIdx.x;
        int r = e >> 6, c = e & 63;
        out[(size_t)(c0 + r) * R + r0 + c] = f2bf(tile[c][r]);
    }
}

// ------------- GEMM: C[M][N] = A[M][K] * Bt[N][K]^T (bf16 in, bf16/f32 out) -------------
__global__ __launch_bounds__(256) void k_gemm_bt(const unsigned short* __restrict__ A,
                                                 const unsigned short* __restrict__ Bt,
                                                 void* __restrict__ Cout,
                                                 int M, int N, int K, int out_f32) {
    __shared__ __align__(16) unsigned short As[128 * 32];
    __shared__ __align__(16) unsigned short Bs[128 * 32];

    const int tid = threadIdx.x;
    const int lane = tid & 63;
    const int w = tid >> 6;
    const int lr = lane & 15;
    const int lg = lane >> 4;
    const int wr = (w >> 1) * 64;
    const int wc = (w & 1) * 64;

    const int m0 = blockIdx.y * 128;
    const int n0 = blockIdx.x * 128;

    const unsigned short* aptr = A + (size_t)(m0 + (tid >> 2)) * K + (tid & 3) * 8;
    const unsigned short* bptr = Bt + (size_t)(n0 + (tid >> 2)) * K + (tid & 3) * 8;

    float4v acc[4][4];
#pragma unroll
    for (int i = 0; i < 4; ++i)
#pragma unroll
        for (int j = 0; j < 4; ++j) acc[i][j] = (float4v){0.f, 0.f, 0.f, 0.f};

    for (int k0 = 0; k0 < K; k0 += 32) {
        gload_lds16(aptr + k0, &As[tid * 8]);
        gload_lds16(aptr + (size_t)64 * K + k0, &As[2048 + tid * 8]);
        gload_lds16(bptr + k0, &Bs[tid * 8]);
        gload_lds16(bptr + (size_t)64 * K + k0, &Bs[2048 + tid * 8]);
        __syncthreads();

        short8v af[4], bf[4];
#pragma unroll
        for (int i = 0; i < 4; ++i)
            af[i] = *(const short8v*)&As[(wr + i * 16 + lr) * 32 + lg * 8];
#pragma unroll
        for (int i = 0; i < 4; ++i)
            bf[i] = *(const short8v*)&Bs[(wc + i * 16 + lr) * 32 + lg * 8];
#pragma unroll
        for (int mi = 0; mi < 4; ++mi)
#pragma unroll
            for (int ni = 0; ni < 4; ++ni)
                acc[mi][ni] = __builtin_amdgcn_mfma_f32_16x16x32_bf16(af[mi], bf[ni],
                                                                      acc[mi][ni], 0, 0, 0);
        __syncthreads();
    }

#pragma unroll
    for (int mi = 0; mi < 4; ++mi) {
#pragma unroll
        for (int ni = 0; ni < 4; ++ni) {
            int row = m0 + wr + mi * 16 + lg * 4;
            int col = n0 + wc + ni * 16 + lr;
            if (out_f32) {
                float* Cf = (float*)Cout;
#pragma unroll
                for (int r = 0; r < 4; ++r) Cf[(size_t)(row + r) * N + col] = acc[mi][ni][r];
            } else {
                unsigned short* Cb = (unsigned short*)Cout;
#pragma unroll
                for (int r = 0; r < 4; ++r) Cb[(size_t)(row + r) * N + col] = f2bf(acc[mi][ni][r]);
            }
        }
    }
}

// ------------- V-part of qkv -> v_t[b,h,d,t] (bf16) -------------
__global__ __launch_bounds__(256) void k_transpose_v(const unsigned short* __restrict__ qkv,
                                                     unsigned short* __restrict__ vt) {
    __shared__ unsigned short tile[64][72];
    int t0 = blockIdx.x * 64;
    int bh = blockIdx.y;
    int b = bh >> 4, h = bh & 15;
#pragma unroll
    for (int i = 0; i < 2; ++i) {
        int e = i * 256 + threadIdx.x;
        int tt = e >> 3, db = (e & 7) * 8;
        short8v v = *(const short8v*)&qkv[(size_t)(b * T_SEQ + t0 + tt) * (3 * C_EMB)
                                          + 2 * C_EMB + h * DH + db];
#pragma unroll
        for (int j = 0; j < 8; ++j) tile[tt][db + j] = (unsigned short)v[j];
    }
    __syncthreads();
#pragma unroll
    for (int i = 0; i < 2; ++i) {
        int e = i * 256 + threadIdx.x;
        int d = e >> 3, tb = (e & 7) * 8;
        short8v ov;
#pragma unroll
        for (int j = 0; j < 8; ++j) ov[j] = (short)tile[tb + j][d];
        *(short8v*)&vt[(size_t)(bh * DH + d) * T_SEQ + t0 + tb] = ov;
    }
}

// ------------- flash attention: 64 q-rows/block, KVBLK=64, dbuf, swizzled LDS -------------
template<bool MASK>
__device__ __forceinline__ void attn_tile(const unsigned short* __restrict__ Ksb,
                                          const unsigned short* __restrict__ Vsb,
                                          unsigned short* __restrict__ Psw,
                                          short8v qa0, short8v qa1, short8v ones,
                                          float4v (&o)[4], float4v& accl, float (&m_run)[4],
                                          int lr, int lg, int qloc) {
    const int swz = lr & 7;
    float4v s[4];
#pragma unroll
    for (int sub = 0; sub < 4; ++sub) {
        const unsigned short* rowp = Ksb + (sub * 16 + lr) * 64;
        short8v kb0 = *(const short8v*)&rowp[(lg ^ swz) * 8];
        short8v kb1 = *(const short8v*)&rowp[((4 + lg) ^ swz) * 8];
        float4v acc = (float4v){0.f, 0.f, 0.f, 0.f};
        acc = __builtin_amdgcn_mfma_f32_16x16x32_bf16(qa0, kb0, acc, 0, 0, 0);
        acc = __builtin_amdgcn_mfma_f32_16x16x32_bf16(qa1, kb1, acc, 0, 0, 0);
        s[sub] = acc;
    }
    if (MASK) {
#pragma unroll
        for (int sub = 0; sub < 4; ++sub)
#pragma unroll
            for (int r = 0; r < 4; ++r)
                s[sub][r] = (sub * 16 + lr <= qloc + r) ? s[sub][r] : -1e30f;
    }
    // running max (keys live across lr lanes + 4 subs in-lane)
    float rmax[4];
#pragma unroll
    for (int r = 0; r < 4; ++r)
        rmax[r] = fmaxf(fmaxf(s[0][r], s[1][r]), fmaxf(s[2][r], s[3][r]));
#pragma unroll
    for (int st = 1; st < 16; st <<= 1)
#pragma unroll
        for (int r = 0; r < 4; ++r) rmax[r] = fmaxf(rmax[r], __shfl_xor(rmax[r], st));

    float dmax = fmaxf(fmaxf(rmax[0] - m_run[0], rmax[1] - m_run[1]),
                       fmaxf(rmax[2] - m_run[2], rmax[3] - m_run[3]));
    if (__any(dmax > DEFER_THR)) {   // rescale path (rare after tile 0)
#pragma unroll
        for (int r = 0; r < 4; ++r) {
            float nm = fmaxf(m_run[r], rmax[r]);
            float alpha = exp2f((m_run[r] - nm) * CEXP);
            m_run[r] = nm;
#pragma unroll
            for (int n = 0; n < 4; ++n) o[n][r] *= alpha;
            accl[r] *= alpha;
        }
    }
    float mnc[4];
#pragma unroll
    for (int r = 0; r < 4; ++r) mnc[r] = m_run[r] * CEXP;

#pragma unroll
    for (int sub = 0; sub < 4; ++sub) {
        float p0 = exp2f(__builtin_fmaf(s[sub][0], CEXP, -mnc[0]));
        float p1 = exp2f(__builtin_fmaf(s[sub][1], CEXP, -mnc[1]));
        float p2 = exp2f(__builtin_fmaf(s[sub][2], CEXP, -mnc[2]));
        float p3 = exp2f(__builtin_fmaf(s[sub][3], CEXP, -mnc[3]));
        unsigned int u0 = cvtpk_bf16(p0, p1);
        unsigned int u1 = cvtpk_bf16(p2, p3);
        Psw[(lg * 4 + 0) * 72 + sub * 16 + lr] = (unsigned short)u0;
        Psw[(lg * 4 + 1) * 72 + sub * 16 + lr] = (unsigned short)(u0 >> 16);
        Psw[(lg * 4 + 2) * 72 + sub * 16 + lr] = (unsigned short)u1;
        Psw[(lg * 4 + 3) * 72 + sub * 16 + lr] = (unsigned short)(u1 >> 16);
    }
    // PV (wave-private Ps: compiler orders ds_write->ds_read via lgkmcnt, no barrier)
#pragma unroll
    for (int kk = 0; kk < 2; ++kk) {
        short8v pa = *(const short8v*)&Psw[lr * 72 + kk * 32 + lg * 8];
        accl = __builtin_amdgcn_mfma_f32_16x16x32_bf16(pa, ones, accl, 0, 0, 0);
#pragma unroll
        for (int n = 0; n < 4; ++n) {
            short8v vb = *(const short8v*)&Vsb[(n * 16 + lr) * 64 + (((kk * 4 + lg) ^ swz)) * 8];
            o[n] = __builtin_amdgcn_mfma_f32_16x16x32_bf16(pa, vb, o[n], 0, 0, 0);
        }
    }
}

__global__ __launch_bounds__(256) void k_attn(const unsigned short* __restrict__ qkv,
                                              const unsigned short* __restrict__ vt,
                                              unsigned short* __restrict__ aout) {
    __shared__ __align__(16) unsigned short Ks[2][64 * 64];
    __shared__ __align__(16) unsigned short Vs[2][64 * 64];
    __shared__ __align__(16) unsigned short Ps[4][16 * 72];

    const int tid = threadIdx.x;
    const int lane = tid & 63;
    const int w = tid >> 6;
    const int lr = lane & 15;
    const int lg = lane >> 4;

    const int bh = blockIdx.x;
    const int q0 = ((int)gridDim.y - 1 - (int)blockIdx.y) * 64;  // heavy blocks first
    const int b = bh >> 4, h = bh & 15;

    // Q fragment (16 q-rows per wave)
    const unsigned short* qrowp =
        qkv + (size_t)(b * T_SEQ + q0 + w * 16 + lr) * (3 * C_EMB) + h * DH + lg * 8;
    short8v qa0 = *(const short8v*)qrowp;
    short8v qa1 = *(const short8v*)(qrowp + 32);

    short8v ones;
#pragma unroll
    for (int j = 0; j < 8; ++j) ones[j] = (short)0x3F80;

    float4v o[4];
    float4v accl = (float4v){0.f, 0.f, 0.f, 0.f};
    float m_run[4];
#pragma unroll
    for (int n = 0; n < 4; ++n) o[n] = (float4v){0.f, 0.f, 0.f, 0.f};
#pragma unroll
    for (int r = 0; r < 4; ++r) m_run[r] = -1e30f;

    // staging sources (pre-swizzled: lc = (chunk ^ row) so linear gload_lds lands swizzled)
    const int lc = ((tid & 7) ^ ((tid >> 3) & 7)) * 8;
    const unsigned short* kbase =
        qkv + (size_t)(b * T_SEQ + (tid >> 3)) * (3 * C_EMB) + C_EMB + h * DH + lc;
    const unsigned short* vbase = vt + (size_t)(bh * DH + (tid >> 3)) * T_SEQ + lc;

    unsigned short* Psw = &Ps[w][0];
    const int qloc = w * 16 + lg * 4;
    const int nt = q0 / 64 + 1;

    // prologue stage tile 0 -> buf 0
    gload_lds16(kbase, &Ks[0][tid * 8]);
    gload_lds16(kbase + (size_t)32 * 3 * C_EMB, &Ks[0][2048 + tid * 8]);
    gload_lds16(vbase, &Vs[0][tid * 8]);
    gload_lds16(vbase + (size_t)32 * T_SEQ, &Vs[0][2048 + tid * 8]);

    int cur = 0;
    for (int t = 0; t < nt - 1; ++t) {
        const size_t kv0 = (size_t)(t + 1) * 64;
        // prefetch next tile into other buffer
        gload_lds16(kbase + kv0 * 3 * C_EMB, &Ks[cur ^ 1][tid * 8]);
        gload_lds16(kbase + (kv0 + 32) * 3 * C_EMB, &Ks[cur ^ 1][2048 + tid * 8]);
        gload_lds16(vbase + kv0, &Vs[cur ^ 1][tid * 8]);
        gload_lds16(vbase + (size_t)32 * T_SEQ + kv0, &Vs[cur ^ 1][2048 + tid * 8]);
        asm volatile("s_waitcnt vmcnt(4)" ::: "memory");   // current tile staged; next in flight
        block_barrier();
        attn_tile<false>(&Ks[cur][0], &Vs[cur][0], Psw, qa0, qa1, ones,
                         o, accl, m_run, lr, lg, qloc);
        block_barrier();
        cur ^= 1;
    }
    // diagonal (masked) tile
    asm volatile("s_waitcnt vmcnt(0)" ::: "memory");
    block_barrier();
    attn_tile<true>(&Ks[cur][0], &Vs[cur][0], Psw, qa0, qa1, ones,
                    o, accl, m_run, lr, lg, qloc);

    float rl[4];
#pragma unroll
    for (int r = 0; r < 4; ++r) rl[r] = 1.0f / accl[r];
    const int trow = b * T_SEQ + q0 + w * 16 + lg * 4;
#pragma unroll
    for (int n = 0; n < 4; ++n)
#pragma unroll
        for (int r = 0; r < 4; ++r)
            aout[(size_t)(trow + r) * C_EMB + h * DH + n * 16 + lr] = f2bf(o[n][r] * rl[r]);
}

extern "C" void kernel_launch(void* const* d_in, const int* in_sizes, int n_in,
                              void* d_out, int out_size, void* d_ws, size_t ws_size,
                              hipStream_t stream) {
    const float* x = (const float*)d_in[0];
    const float* Wqkv = (const float*)d_in[1];
    const float* Wproj = (const float*)d_in[2];
    float* out = (float*)d_out;

    unsigned short* xb     = (unsigned short*)d_ws;
    unsigned short* wqkvT  = xb + (size_t)M_ROWS * C_EMB;
    unsigned short* wprojT = wqkvT + (size_t)3 * C_EMB * C_EMB;
    unsigned short* qkvb   = wprojT + (size_t)C_EMB * C_EMB;
    unsigned short* vtb    = qkvb + (size_t)M_ROWS * 3 * C_EMB;
    unsigned short* attb   = vtb + (size_t)M_ROWS * C_EMB;

    k_cvt_x<<<(M_ROWS * C_EMB / 4 + 255) / 256, 256, 0, stream>>>(x, xb, M_ROWS * C_EMB / 4);
    k_transpose_cvt<<<dim3(3 * C_EMB / 64, C_EMB / 64), 256, 0, stream>>>(Wqkv, wqkvT, C_EMB, 3 * C_EMB);
    k_transpose_cvt<<<dim3(C_EMB / 64, C_EMB / 64), 256, 0, stream>>>(Wproj, wprojT, C_EMB, C_EMB);
    k_gemm_bt<<<dim3(3 * C_EMB / 128, M_ROWS / 128), 256, 0, stream>>>(xb, wqkvT, (void*)qkvb,
                                                                       M_ROWS, 3 * C_EMB, C_EMB, 0);
    k_transpose_v<<<dim3(T_SEQ / 64, B_SZ * NH), 256, 0, stream>>>(qkvb, vtb);
    k_attn<<<dim3(B_SZ * NH, T_SEQ / 64), 256, 0, stream>>>(qkvb, vtb, attb);
    k_gemm_bt<<<dim3(C_EMB / 128, M_ROWS / 128), 256, 0, stream>>>(attb, wprojT, (void*)out,
                                                                   M_ROWS, C_EMB, C_EMB, 1);
}